// Round 2
// baseline (69.839 us; speedup 1.0000x reference)
//
#include <hip/hip_runtime.h>
#include <hip/hip_bf16.h>

// Problem constants from reference setup_inputs(): B=256, D=512, fp32.
#define BB 256
#define DD 512

// Single fused kernel, one block of 1024 threads on one CU.
// Thread t handles column d = t & 511, row-half h = t >> 9 (128 rows each).
// Per-column stats: A = sum(exp(lv) + mu^2), P = sum(exp(-lv)),
//                   M = sum(mu), Q = sum(mu*exp(-lv)), R = sum(mu^2*exp(-lv))
// Closed form (diagonal KL(i,i)=0 exactly, so include it):
//   Full = sum_d (A*P - 2*M*Q + B*R)   [includes the -1 term separately]
//   answer = (Full - D*B^2) / (2B)
__global__ __launch_bounds__(1024) void udl_fused(const float* __restrict__ mu,
                                                  const float* __restrict__ lv,
                                                  float* __restrict__ out) {
    const int d = threadIdx.x & (DD - 1);   // 0..511
    const int h = threadIdx.x >> 9;         // 0 or 1
    const int row0 = h * (BB / 2);

    float A = 0.f, P = 0.f, M = 0.f, Q = 0.f, R = 0.f;
#pragma unroll 8
    for (int r = 0; r < BB / 2; ++r) {
        const int idx = (row0 + r) * DD + d;   // coalesced across the wave
        const float m = mu[idx];
        const float l = lv[idx];
        const float ev = __expf(l);
        const float iv = __expf(-l);
        A += ev + m * m;
        P += iv;
        M += m;
        const float miv = m * iv;
        Q += miv;
        R += m * miv;
    }

    // Combine the two row-halves per column through LDS (10 KB).
    __shared__ float sA[DD], sP[DD], sM[DD], sQ[DD], sR[DD];
    if (h == 1) { sA[d] = A; sP[d] = P; sM[d] = M; sQ[d] = Q; sR[d] = R; }
    __syncthreads();

    double cd = 0.0;
    if (h == 0) {
        const double Af = (double)A + (double)sA[d];
        const double Pf = (double)P + (double)sP[d];
        const double Mf = (double)M + (double)sM[d];
        const double Qf = (double)Q + (double)sQ[d];
        const double Rf = (double)R + (double)sR[d];
        cd = Af * Pf - 2.0 * Mf * Qf + (double)BB * Rf;
    }

    // Block reduce: wave shuffle (h==1 lanes contribute 0), then LDS across 16 waves.
    for (int off = 32; off > 0; off >>= 1)
        cd += __shfl_down(cd, off, 64);

    __shared__ double sred[1024 / 64];
    const int wid = threadIdx.x >> 6;
    const int lane = threadIdx.x & 63;
    if (lane == 0) sred[wid] = cd;
    __syncthreads();

    if (threadIdx.x == 0) {
        double full = 0.0;
#pragma unroll
        for (int w = 0; w < 1024 / 64; ++w) full += sred[w];
        const double result = (full - (double)DD * (double)BB * (double)BB)
                              / (2.0 * (double)BB);
        out[0] = (float)result;
    }
}

extern "C" void kernel_launch(void* const* d_in, const int* in_sizes, int n_in,
                              void* d_out, int out_size, void* d_ws, size_t ws_size,
                              hipStream_t stream) {
    const float* mu = (const float*)d_in[0];
    const float* lv = (const float*)d_in[1];
    float* out = (float*)d_out;

    udl_fused<<<1, 1024, 0, stream>>>(mu, lv, out);
}

// Round 3
// 63.715 us; speedup vs baseline: 1.0961x; 1.0961x over previous
//
#include <hip/hip_runtime.h>
#include <hip/hip_bf16.h>

// Problem constants from reference setup_inputs(): B=256, D=512, fp32.
#define BB 256
#define DD 512
#define NCH 16                 // row chunks / blocks
#define RPC (BB / NCH)         // 16 rows per chunk

#define POISON 0xAAAAAAAAu

// Single launch, 16 blocks x 512 threads. Block c computes per-column partial
// stats over rows [c*16, c*16+16) and writes them to distinct ws slots (no
// zero-init needed). A ticket counter (reset from harness poison via CAS)
// elects the last-finished block to combine everything and write the scalar.
//
// Stats per column d: A = sum(exp(lv) + mu^2), P = sum(exp(-lv)),
//                     M = sum(mu), Q = sum(mu*exp(-lv)), R = sum(mu^2*exp(-lv))
// Closed form: Full = sum_d (A*P - 2*M*Q + B*R);  answer = (Full - D*B^2)/(2B)
__global__ __launch_bounds__(512) void udl_onekernel(const float* __restrict__ mu,
                                                     const float* __restrict__ lv,
                                                     float* __restrict__ out,
                                                     float* __restrict__ ws,
                                                     unsigned int* __restrict__ counter) {
    const int d = threadIdx.x;        // 0..511
    const int chunk = blockIdx.x;     // 0..15
    const int row0 = chunk * RPC;

    float A = 0.f, P = 0.f, M = 0.f, Q = 0.f, R = 0.f;
#pragma unroll
    for (int r = 0; r < RPC; ++r) {
        const int idx = (row0 + r) * DD + d;   // coalesced across the wave
        const float m = mu[idx];
        const float l = lv[idx];
        const float ev = __expf(l);
        const float iv = __expf(-l);
        A += ev + m * m;
        P += iv;
        M += m;
        const float miv = m * iv;
        Q += miv;
        R += m * miv;
    }
    float* o = ws + (size_t)chunk * 5 * DD;
    o[0 * DD + d] = A;
    o[1 * DD + d] = P;
    o[2 * DD + d] = M;
    o[3 * DD + d] = Q;
    o[4 * DD + d] = R;

    // Make this block's partials device-visible, then take a ticket.
    __threadfence();
    __syncthreads();

    __shared__ int s_last;
    if (threadIdx.x == 0) {
        // Exactly-once reset of the poisoned counter: every block CASes
        // before it increments, and CAS only succeeds on the poison value.
        atomicCAS(counter, POISON, 0u);
        const unsigned int ticket = atomicAdd(counter, 1u);
        s_last = (ticket == NCH - 1) ? 1 : 0;
    }
    __syncthreads();
    if (!s_last) return;

    // Last block: all other blocks' partials are visible (release via
    // threadfence+atomic, acquire via atomic+threadfence).
    __threadfence();

    float Af = 0.f, Pf = 0.f, Mf = 0.f, Qf = 0.f, Rf = 0.f;
#pragma unroll
    for (int c = 0; c < NCH; ++c) {
        const float* p = ws + (size_t)c * 5 * DD;
        Af += p[0 * DD + d];
        Pf += p[1 * DD + d];
        Mf += p[2 * DD + d];
        Qf += p[3 * DD + d];
        Rf += p[4 * DD + d];
    }
    double cd = (double)Af * (double)Pf
              - 2.0 * (double)Mf * (double)Qf
              + (double)BB * (double)Rf;

    // wave (64-lane) shuffle reduce, then LDS across the 8 waves
    for (int off = 32; off > 0; off >>= 1)
        cd += __shfl_down(cd, off, 64);

    __shared__ double sred[DD / 64];
    const int wid = threadIdx.x >> 6;
    const int lane = threadIdx.x & 63;
    if (lane == 0) sred[wid] = cd;
    __syncthreads();

    if (threadIdx.x == 0) {
        double full = 0.0;
#pragma unroll
        for (int w = 0; w < DD / 64; ++w) full += sred[w];
        const double result = (full - (double)DD * (double)BB * (double)BB)
                              / (2.0 * (double)BB);
        out[0] = (float)result;
    }
}

extern "C" void kernel_launch(void* const* d_in, const int* in_sizes, int n_in,
                              void* d_out, int out_size, void* d_ws, size_t ws_size,
                              hipStream_t stream) {
    const float* mu = (const float*)d_in[0];
    const float* lv = (const float*)d_in[1];
    float* out = (float*)d_out;
    float* ws = (float*)d_ws;
    // partials occupy NCH*5*DD floats = 160 KB; counter lives right after.
    unsigned int* counter = (unsigned int*)(ws + (size_t)NCH * 5 * DD);

    udl_onekernel<<<NCH, DD, 0, stream>>>(mu, lv, out, ws, counter);
}

// Round 4
// 60.381 us; speedup vs baseline: 1.1566x; 1.0552x over previous
//
#include <hip/hip_runtime.h>
#include <hip/hip_bf16.h>

// Problem constants from reference setup_inputs(): B=256, D=512, fp32.
#define BB 256
#define DD 512
#define NCHUNK 8              // row chunks in phase 1
#define ROWS_PER_CHUNK (BB / NCHUNK)   // 32

// Best-measured structure (R1, 60.4 us): two tiny launches.
// R2 (1-block fused): +9.4 us — 1-CU serialization of 262144 transcendentals.
// R3 (1-launch ticket/fence): +3.3 us — device-scope fence + last-block wait
// costs more than the graph's kernel->kernel gap. Keep two launches.
//
// Phase 1: per-column (per-d) partial sums over a 32-row chunk.
// Stats per d: A = sum(exp(lv) + mu^2), P = sum(exp(-lv)),
//              M = sum(mu), Q = sum(mu*exp(-lv)), R = sum(mu^2*exp(-lv))
// ws layout: ws[chunk][stat(5)][DD] floats  -> 8*5*512*4 = 80 KB
__global__ void udl_phase1(const float* __restrict__ mu,
                           const float* __restrict__ lv,
                           float* __restrict__ ws) {
    const int d = threadIdx.x;        // 0..511
    const int chunk = blockIdx.x;     // 0..7
    const int row0 = chunk * ROWS_PER_CHUNK;

    float A = 0.f, P = 0.f, M = 0.f, Q = 0.f, R = 0.f;
#pragma unroll 4
    for (int r = 0; r < ROWS_PER_CHUNK; ++r) {
        const int idx = (row0 + r) * DD + d;   // coalesced: contiguous across threads
        const float m = mu[idx];
        const float l = lv[idx];
        const float ev = __expf(l);
        const float iv = __expf(-l);
        A += ev + m * m;
        P += iv;
        M += m;
        const float miv = m * iv;
        Q += miv;
        R += m * miv;
    }
    float* o = ws + (size_t)chunk * 5 * DD;
    o[0 * DD + d] = A;
    o[1 * DD + d] = P;
    o[2 * DD + d] = M;
    o[3 * DD + d] = Q;
    o[4 * DD + d] = R;
}

// Phase 2: combine chunk partials per d, form c[d] = A*P - 2*M*Q + B*R,
// block-reduce over d (double), apply closed form, write scalar.
// Closed form: Full = sum_d (A*P - 2*M*Q + B*R);  answer = (Full - D*B^2)/(2B)
__global__ void udl_phase2(const float* __restrict__ ws,
                           float* __restrict__ out) {
    const int d = threadIdx.x;        // 512 threads, one per column
    float A = 0.f, P = 0.f, M = 0.f, Q = 0.f, R = 0.f;
#pragma unroll
    for (int c = 0; c < NCHUNK; ++c) {
        const float* o = ws + (size_t)c * 5 * DD;
        A += o[0 * DD + d];
        P += o[1 * DD + d];
        M += o[2 * DD + d];
        Q += o[3 * DD + d];
        R += o[4 * DD + d];
    }
    double cd = (double)A * (double)P
              - 2.0 * (double)M * (double)Q
              + (double)BB * (double)R;

    // wave (64-lane) shuffle reduce, then LDS across the 8 waves
    for (int off = 32; off > 0; off >>= 1)
        cd += __shfl_down(cd, off, 64);

    __shared__ double sred[DD / 64];
    const int wid = threadIdx.x >> 6;
    const int lane = threadIdx.x & 63;
    if (lane == 0) sred[wid] = cd;
    __syncthreads();

    if (threadIdx.x == 0) {
        double full = 0.0;
#pragma unroll
        for (int w = 0; w < DD / 64; ++w) full += sred[w];
        // answer = (Full - D*B^2) / (2B)
        const double result = (full - (double)DD * (double)BB * (double)BB)
                              / (2.0 * (double)BB);
        out[0] = (float)result;
    }
}

extern "C" void kernel_launch(void* const* d_in, const int* in_sizes, int n_in,
                              void* d_out, int out_size, void* d_ws, size_t ws_size,
                              hipStream_t stream) {
    const float* mu = (const float*)d_in[0];
    const float* lv = (const float*)d_in[1];
    float* out = (float*)d_out;
    float* ws = (float*)d_ws;

    udl_phase1<<<NCHUNK, DD, 0, stream>>>(mu, lv, ws);
    udl_phase2<<<1, DD, 0, stream>>>(ws, out);
}